// Round 10
// baseline (164.662 us; speedup 1.0000x reference)
//
#include <hip/hip_runtime.h>
#include <math.h>
#include <stdint.h>

#define SEQ  2048
#define LOG2E 1.4426950408889634f

typedef __attribute__((ext_vector_type(4))) float f32x4;
typedef __attribute__((ext_vector_type(16))) float f32x16;
typedef __attribute__((ext_vector_type(8))) short bf16x8;

template <int V> struct IC { static constexpr int value = V; };

// pack two fp32 -> bf16x2 dword via v_perm (round-half-up; ties-only diff vs RNE)
__device__ __forceinline__ unsigned packbf(float a, float b) {
    return __builtin_amdgcn_perm(__float_as_uint(b) + 0x8000u,
                                 __float_as_uint(a) + 0x8000u, 0x07060302u);
}

// async global->LDS, 16B/lane. LDS dest = wave-uniform base + lane*16 (HW).
// Global src is PER-LANE -> pre-permute the source so the linear LDS image
// equals the MFMA frag image (m173 pattern; mapping harness-verified in R6).
__device__ __forceinline__ void gload16(const unsigned short* g, unsigned short* l) {
    __builtin_amdgcn_global_load_lds(
        (const __attribute__((address_space(1))) unsigned int*)g,
        (__attribute__((address_space(3))) unsigned int*)l, 16, 0, 0);
}

// ---------------------------------------------------------------------------
// Prepass: convert x (4.2M elems) and Wq/Wk/Wv/Wp (262144 each) fp32->bf16.
// ---------------------------------------------------------------------------
__global__ __launch_bounds__(256) void cvt_kernel(
    const float* __restrict__ x,  const float* __restrict__ wq,
    const float* __restrict__ wk, const float* __restrict__ wv,
    const float* __restrict__ wp,
    unsigned short* __restrict__ xb,  unsigned short* __restrict__ wqb,
    unsigned short* __restrict__ wkb, unsigned short* __restrict__ wvb,
    unsigned short* __restrict__ wpb)
{
    const int c = blockIdx.x * 256 + threadIdx.x;
    const float* s;
    unsigned short* d;
    int off;
    if (c < 524288) {                 // x: 4194304/8 chunks
        s = x; d = xb; off = c;
    } else {
        const int cc = c - 524288;
        const int wsel = cc >> 15;    // 0..3, 32768 chunks each
        off = cc & 32767;
        s = wsel == 0 ? wq : wsel == 1 ? wk : wsel == 2 ? wv : wp;
        d = wsel == 0 ? wqb : wsel == 1 ? wkb : wsel == 2 ? wvb : wpb;
    }
    const float4* sp = (const float4*)s + (size_t)off * 2;
    const float4 a = sp[0], b = sp[1];
    uint4 p;
    p.x = packbf(a.x, a.y); p.y = packbf(a.z, a.w);
    p.z = packbf(b.x, b.y); p.w = packbf(b.z, b.w);
    *((uint4*)d + off) = p;
}

// ---------------------------------------------------------------------------
// QKV GEMM, bf16 operands. C = x(M,512) @ W(N,512)^T + bias, N=1536 (Q|K|V),
// grid (12,64), 128x128 tiles. R10: m97-EXACT skeleton — single 16 KB LDS
// buffer, global_load_lds width=16 direct, BK=32, stage -> barrier ->
// 16 MFMA -> barrier. (R6's failure paired gload_lds with a runtime-indexed
// double buffer: compiler must conservatively drain vmcnt before ds_reads.
// Single-buffer has no cross-barrier aliasing; overlap comes from 3 blk/CU —
// the measured 874-vs-517 TF lever at exactly this tile, m97 vs m93.)
// Per-lane pre-permuted global source keeps the LDS image frag-linear:
//   As[g][i][8] = x[m0 + (g&3)*16 + (i&15) + 64*(g>>2)][k0 + (i>>4)*8 + 0..7]
// Frag-linear outputs (exact MFMA fragment image; attn reads straight from L2):
//   Q'/K': [bh][q32tile(64)][kt(4)][lane(64)][8]   (TR orientation; Q *LOG2E)
//   V'   : [bh][j64tile(32)][dg*4+p(8)][lane(64)][8]
// ---------------------------------------------------------------------------
__global__ __launch_bounds__(256, 3) void qkv_kernel(
    const unsigned short* __restrict__ xb, const unsigned short* __restrict__ wqb,
    const unsigned short* __restrict__ wkb, const unsigned short* __restrict__ wvb,
    const float* __restrict__ bq, const float* __restrict__ bk,
    const float* __restrict__ bv,
    unsigned short* __restrict__ Qw, unsigned short* __restrict__ Kw,
    unsigned short* __restrict__ VTw)
{
    __shared__ __align__(16) unsigned short smem[8192];   // As 4096 | Bs 4096
    unsigned short* As = smem;
    unsigned short* Bs = smem + 4096;

    const int t = threadIdx.x;
    const int w = t >> 6, lane = t & 63, quad = (t >> 4) & 3, l15 = t & 15;
    const int wr = w >> 1, wc = w & 1;
    const int m0 = blockIdx.y * 128;
    const int n0 = blockIdx.x * 128;
    const int which = n0 >> 9;                 // 0=Q 1=K 2=V
    const unsigned short* wbase = which == 0 ? wqb : (which == 1 ? wkb : wvb);
    const int nrow = n0 & 511;

    // per-lane pre-permuted global sources (row = +w*16 + (lane&15), col chunk = lane>>4)
    const unsigned short* axg = xb + (size_t)(m0 + w * 16 + (lane & 15)) * 512 + ((lane >> 4) * 8);
    const unsigned short* bxg = wbase + (size_t)(nrow + w * 16 + (lane & 15)) * 512 + ((lane >> 4) * 8);

    f32x4 acc[4][4];
#pragma unroll
    for (int mt = 0; mt < 4; ++mt)
#pragma unroll
        for (int nt = 0; nt < 4; ++nt) acc[mt][nt] = (f32x4){0.f, 0.f, 0.f, 0.f};

    auto stage = [&](int k0) {
        unsigned short* Ad = As + w * 512;      // group w
        unsigned short* Bd = Bs + w * 512;
        gload16(axg + k0, Ad);
        gload16(axg + 32768 + k0, Ad + 2048);   // group w+4 (rows +64)
        gload16(bxg + k0, Bd);
        gload16(bxg + 32768 + k0, Bd + 2048);
    };

    auto kloop = [&](auto TRC) {
        constexpr int TR = decltype(TRC)::value;
        for (int ki = 0; ki < 16; ++ki) {
            stage(ki * 32);
            __syncthreads();                    // vmcnt(0) drain + barrier
            bf16x8 af[4], bfr[4];
#pragma unroll
            for (int mt = 0; mt < 4; ++mt)
                af[mt] = *(const bf16x8*)(As + ((wr * 4 + mt) * 64 + lane) * 8);
#pragma unroll
            for (int nt = 0; nt < 4; ++nt)
                bfr[nt] = *(const bf16x8*)(Bs + ((wc * 4 + nt) * 64 + lane) * 8);
#pragma unroll
            for (int mt = 0; mt < 4; ++mt)
#pragma unroll
                for (int nt = 0; nt < 4; ++nt) {
                    if (TR)
                        acc[mt][nt] = __builtin_amdgcn_mfma_f32_16x16x32_bf16(
                            bfr[nt], af[mt], acc[mt][nt], 0, 0, 0);
                    else
                        acc[mt][nt] = __builtin_amdgcn_mfma_f32_16x16x32_bf16(
                            af[mt], bfr[nt], acc[mt][nt], 0, 0, 0);
                }
            if (ki < 15) __syncthreads();       // all reads done before re-stage
        }
    };
    if (which < 2) kloop(IC<1>{});
    else           kloop(IC<0>{});

    if (which == 2) {
        // V: normal orientation -> frag-linear V'
#pragma unroll
        for (int nt = 0; nt < 4; ++nt) {
            const int n = n0 + wc * 64 + nt * 16 + l15;
            const float bias = bv[n & 511];
            const int h = (n >> 6) & 7, d = n & 63;
#pragma unroll
            for (int mt = 0; mt < 4; ++mt) {
                const int mb = m0 + wr * 64 + mt * 16 + quad * 4;
                const int bi = mb >> 11, ns = mb & 2047;
                const int bhl = bi * 8 + h;
                const f32x4 v = acc[mt][nt];
                uint2 pk;
                pk.x = packbf(v[0] + bias, v[1] + bias);
                pk.y = packbf(v[2] + bias, v[3] + bias);
                const size_t off =
                    ((size_t)(bhl * 32 + (ns >> 6)) * 8 + ((d >> 5) << 2) +
                     ((ns >> 4) & 3)) * 512 +
                    ((d & 31) << 3) + ((ns & 8) << 5) + (ns & 7);
                *(uint2*)(VTw + off) = pk;
            }
        }
    } else {
        // Q/K: TR orientation -> frag-linear Q'/K'
        const float sc = which ? 1.f : LOG2E;
        const float* bpt = which ? bk : bq;
        unsigned short* base = which ? Kw : Qw;
#pragma unroll
        for (int nt = 0; nt < 4; ++nt) {
            const int nb = n0 + wc * 64 + nt * 16 + quad * 4;   // d base
            const f32x4 bvv = *(const f32x4*)(bpt + (nb & 511));
            const int h = (nb >> 6) & 7, d0 = nb & 63;
#pragma unroll
            for (int mt = 0; mt < 4; ++mt) {
                const int nsg = m0 + wr * 64 + mt * 16 + l15;   // ns (col=l15)
                const int bi = nsg >> 11, ns = nsg & 2047;
                const int bhl = bi * 8 + h;
                const f32x4 v = acc[mt][nt];
                uint2 pk;
                pk.x = packbf((v[0] + bvv[0]) * sc, (v[1] + bvv[1]) * sc);
                pk.y = packbf((v[2] + bvv[2]) * sc, (v[3] + bvv[3]) * sc);
                const size_t off =
                    ((size_t)(bhl * 64 + (ns >> 5)) * 4 + (d0 >> 4)) * 512 +
                    ((d0 & 8) << 5) + ((ns & 31) << 3) + (d0 & 7);
                *(uint2*)(base + off) = pk;
            }
        }
    }
}

// ---------------------------------------------------------------------------
// Out-projection GEMM: out = Owb(M,512) @ Wp(512,512)^T + bp, fp32 out.
// 128x128 tiles, grid (4,64), BK=64, reg-staged (unchanged from R8).
// ---------------------------------------------------------------------------
__global__ __launch_bounds__(256, 3) void outproj_kernel(
    const unsigned short* __restrict__ Aw, const unsigned short* __restrict__ wpb,
    const float* __restrict__ bp, float* __restrict__ out)
{
    __shared__ __align__(16) unsigned short smem[16384];  // As 8192 | Bs 8192
    unsigned short* As = smem;
    unsigned short* Bs = smem + 8192;

    const int t = threadIdx.x;
    const int w = t >> 6, lane = t & 63, quad = (t >> 4) & 3, l15 = t & 15;
    const int wr = w >> 1, wc = w & 1;
    const int m0 = blockIdx.y * 128;
    const int n0 = blockIdx.x * 128;

    const int ar = t >> 2, ac = t & 3;
    const unsigned short* ap = Aw + (size_t)(m0 + ar) * 512 + ac * 8;
    const unsigned short* bx = wpb + (size_t)(n0 + ar) * 512 + ac * 8;
    const int lws = (ar & 15) | (ac << 4);
    const int off0 = (ar >> 4) * 512 + lws * 8;

    f32x4 acc[4][4];
#pragma unroll
    for (int mt = 0; mt < 4; ++mt)
#pragma unroll
        for (int nt = 0; nt < 4; ++nt) acc[mt][nt] = (f32x4){0.f, 0.f, 0.f, 0.f};

    uint4 ra0, ra1, ra2, ra3, rb0, rb1, rb2, rb3;
    auto loadt = [&](int k0) {
        ra0 = *(const uint4*)(ap + k0);
        ra1 = *(const uint4*)(ap + k0 + 32);
        ra2 = *(const uint4*)(ap + 32768 + k0);
        ra3 = *(const uint4*)(ap + 32768 + k0 + 32);
        rb0 = *(const uint4*)(bx + k0);
        rb1 = *(const uint4*)(bx + k0 + 32);
        rb2 = *(const uint4*)(bx + 32768 + k0);
        rb3 = *(const uint4*)(bx + 32768 + k0 + 32);
    };
    auto writet = [&]() {
        *(uint4*)(As + off0) = ra0;
        *(uint4*)(As + off0 + 4096) = ra1;
        *(uint4*)(As + off0 + 2048) = ra2;
        *(uint4*)(As + off0 + 2048 + 4096) = ra3;
        *(uint4*)(Bs + off0) = rb0;
        *(uint4*)(Bs + off0 + 4096) = rb1;
        *(uint4*)(Bs + off0 + 2048) = rb2;
        *(uint4*)(Bs + off0 + 2048 + 4096) = rb3;
    };

    loadt(0);
    for (int ki = 0; ki < 8; ++ki) {
        writet();
        if (ki < 7) loadt((ki + 1) * 64);
        __syncthreads();
#pragma unroll
        for (int s = 0; s < 2; ++s) {
            bf16x8 af[4], bfr[4];
#pragma unroll
            for (int mt = 0; mt < 4; ++mt)
                af[mt] = *(const bf16x8*)(As + s * 4096 +
                                          ((wr * 4 + mt) * 64 + lane) * 8);
#pragma unroll
            for (int nt = 0; nt < 4; ++nt)
                bfr[nt] = *(const bf16x8*)(Bs + s * 4096 +
                                           ((wc * 4 + nt) * 64 + lane) * 8);
#pragma unroll
            for (int mt = 0; mt < 4; ++mt)
#pragma unroll
                for (int nt = 0; nt < 4; ++nt)
                    acc[mt][nt] = __builtin_amdgcn_mfma_f32_16x16x32_bf16(
                        af[mt], bfr[nt], acc[mt][nt], 0, 0, 0);
        }
        if (ki < 7) __syncthreads();
    }

#pragma unroll
    for (int nt = 0; nt < 4; ++nt) {
        const int n = n0 + wc * 64 + nt * 16 + l15;
        const float bias = bp[n];
#pragma unroll
        for (int mt = 0; mt < 4; ++mt) {
            const int mb = m0 + wr * 64 + mt * 16 + quad * 4;
            const f32x4 v = acc[mt][nt];
#pragma unroll
            for (int r = 0; r < 4; ++r)
                out[(size_t)(mb + r) * 512 + n] = v[r] + bias;
        }
    }
}

// ---------------------------------------------------------------------------
// bf16 32x32x16-MFMA flash attention — zero LDS/barriers in the K-loop.
// Grid (32,16) x 512 threads, launch_bounds(512,2). 2-deep S pipeline
// (stA/stB), K prefetch distance 2, T12 P-frag. (Exact R5 kernel — best
// measured 47.0 us; R9's diagnostic half-split reverted.)
// End: one LDS merge adds (O,l) across the jh pair; jh=0 stores.
// att = softmax(unscaled)/sqrt(512)
// ---------------------------------------------------------------------------
#define ATTN_STEP(STC, STN, JT)                                                \
    do {                                                                       \
        const int jt_ = (JT);                                                  \
        bf16x8 vc[4];                                                          \
        _Pragma("unroll")                                                      \
        for (int dg = 0; dg < 2; ++dg)                                         \
            _Pragma("unroll")                                                  \
            for (int p = 0; p < 2; ++p)                                        \
                vc[dg * 2 + p] = *(const bf16x8*)(                             \
                    Vp + (size_t)jt_ * 4096 + (dg * 4 + jh * 2 + p) * 512);    \
        STN = zero;                                                            \
        __builtin_amdgcn_s_setprio(1);                                         \
        _Pragma("unroll")                                                      \
        for (int kt = 0; kt < 4; ++kt)                                         \
            STN = __builtin_amdgcn_mfma_f32_32x32x16_bf16(kc[kt], qf[kt],      \
                                                          STN, 0, 0, 0);       \
        __builtin_amdgcn_s_setprio(0);                                         \
        const int jn_ = (jt_ < 30) ? jt_ + 2 : 31;                             \
        _Pragma("unroll")                                                      \
        for (int c = 0; c < 4; ++c)                                            \
            kc[c] = *(const bf16x8*)(Kp + (size_t)jn_ * 4096 + c * 512);       \
        _Pragma("unroll")                                                      \
        for (int r = 0; r < 16; ++r)                                           \
            STC[r] = __builtin_amdgcn_exp2f(STC[r]);                           \
        {                                                                      \
            float s01 = STC[0] + STC[1],   s23 = STC[2] + STC[3];              \
            float s45 = STC[4] + STC[5],   s67 = STC[6] + STC[7];              \
            float s89 = STC[8] + STC[9],   sAB = STC[10] + STC[11];            \
            float sCD = STC[12] + STC[13], sEF = STC[14] + STC[15];            \
            lpart += ((s01 + s23) + (s45 + s67)) + ((s89 + sAB) + (sCD + sEF));\
        }                                                                      \
        _Pragma("unroll")                                                      \
        for (int p = 0; p < 2; ++p) {                                          \
            const int r0 = p * 8;                                              \
            unsigned a0, a1, b0, b1;                                           \
            asm("v_cvt_pk_bf16_f32 %0, %1, %2"                                 \
                : "=v"(a0) : "v"(STC[r0 + 0]), "v"(STC[r0 + 1]));              \
            asm("v_cvt_pk_bf16_f32 %0, %1, %2"                                 \
                : "=v"(a1) : "v"(STC[r0 + 2]), "v"(STC[r0 + 3]));              \
            asm("v_cvt_pk_bf16_f32 %0, %1, %2"                                 \
                : "=v"(b0) : "v"(STC[r0 + 4]), "v"(STC[r0 + 5]));              \
            asm("v_cvt_pk_bf16_f32 %0, %1, %2"                                 \
                : "=v"(b1) : "v"(STC[r0 + 6]), "v"(STC[r0 + 7]));              \
            asm("v_permlane32_swap_b32 %0, %1" : "+v"(a0), "+v"(b0));          \
            asm("v_permlane32_swap_b32 %0, %1" : "+v"(a1), "+v"(b1));          \
            union { unsigned u[4]; bf16x8 v; } pb;                             \
            pb.u[0] = a0;                                                      \
            pb.u[1] = a1;                                                      \
            pb.u[2] = b0;                                                      \
            pb.u[3] = b1;                                                      \
            __builtin_amdgcn_s_setprio(1);                                     \
            Ot[0] = __builtin_amdgcn_mfma_f32_32x32x16_bf16(vc[0 + p], pb.v,   \
                                                            Ot[0], 0, 0, 0);   \
            Ot[1] = __builtin_amdgcn_mfma_f32_32x32x16_bf16(vc[2 + p], pb.v,   \
                                                            Ot[1], 0, 0, 0);   \
            __builtin_amdgcn_s_setprio(0);                                     \
        }                                                                      \
    } while (0)

__global__ __launch_bounds__(512, 2) void attn_kernel(
    const unsigned short* __restrict__ Qf, const unsigned short* __restrict__ Kf,
    const unsigned short* __restrict__ Vf, unsigned short* __restrict__ Ow)
{
    __shared__ float cb[8448];   // O partials 8192 + l partials 256
    const int t = threadIdx.x;
    const int w = t >> 6, lane = t & 63;
    const int l31 = lane & 31, hlf = lane >> 5;
    const int qi = w >> 1, jh = w & 1;

    const int bh = blockIdx.x;          // bh%8 pins one (b,h) to one XCD
    const int qblk = blockIdx.y;        // 0..15
    const int q0 = qblk * 128;

    const unsigned short* Kp = Kf + (size_t)bh * 131072 + (jh * 4) * 512 + lane * 8;
    const unsigned short* Vp = Vf + (size_t)bh * 131072 + lane * 8;

    const int qgg = qblk * 4 + qi;
    const unsigned short* Qp = Qf + ((size_t)(bh * 64 + qgg) * 4) * 512 + lane * 8;
    bf16x8 qf[4];
#pragma unroll
    for (int kt = 0; kt < 4; ++kt)
        qf[kt] = *(const bf16x8*)(Qp + kt * 512);

    f32x16 zero;
#pragma unroll
    for (int r = 0; r < 16; ++r) zero[r] = 0.f;

    float lpart = 0.f;
    f32x16 Ot[2];
    Ot[0] = zero; Ot[1] = zero;

    // ---- prologue: S[0] from K[0]; then kc <- K[1] ----
    bf16x8 kc[4];
#pragma unroll
    for (int c = 0; c < 4; ++c)
        kc[c] = *(const bf16x8*)(Kp + c * 512);

    f32x16 stA = zero, stB = zero;
#pragma unroll
    for (int kt = 0; kt < 4; ++kt)
        stA = __builtin_amdgcn_mfma_f32_32x32x16_bf16(kc[kt], qf[kt], stA, 0, 0, 0);
#pragma unroll
    for (int c = 0; c < 4; ++c)
        kc[c] = *(const bf16x8*)(Kp + 4096 + c * 512);

    for (int jt = 0; jt < 32; jt += 2) {
        ATTN_STEP(stA, stB, jt);        // PV[jt],   S[jt+1] -> stB
        ATTN_STEP(stB, stA, jt + 1);    // PV[jt+1], S[jt+2] -> stA
    }

    // ---- merge (O, l) across the jh pair; jh=0 stores ----
    if (jh == 1) {
#pragma unroll
        for (int dg = 0; dg < 2; ++dg) {
            const int cidx = (qi * 2 + dg) * 4;
#pragma unroll
            for (int k = 0; k < 4; ++k) {
                float4 v = make_float4(
                    Ot[dg][k * 4 + 0], Ot[dg][k * 4 + 1],
                    Ot[dg][k * 4 + 2], Ot[dg][k * 4 + 3]);
                *(float4*)(cb + (cidx + k) * 256 + lane * 4) = v;
            }
        }
        cb[8192 + qi * 64 + lane] = lpart;
    }
    __syncthreads();
    if (jh == 0) {
        const int bi = bh >> 3, h = bh & 7;
#pragma unroll
        for (int dg = 0; dg < 2; ++dg) {
            const int cidx = (qi * 2 + dg) * 4;
#pragma unroll
            for (int k = 0; k < 4; ++k) {
                const float4 v = *(const float4*)(cb + (cidx + k) * 256 + lane * 4);
                Ot[dg][k * 4 + 0] += v.x;
                Ot[dg][k * 4 + 1] += v.y;
                Ot[dg][k * 4 + 2] += v.z;
                Ot[dg][k * 4 + 3] += v.w;
            }
        }
        float lv = lpart + cb[8192 + qi * 64 + lane];
        lv += __shfl_xor(lv, 32);
        const float inv = 1.0f / (lv * 22.627416997969522f);

        const int ns = q0 + qi * 32 + l31;
        unsigned short* dst = Ow + ((size_t)bi * SEQ + ns) * 512 + h * 64 + hlf * 4;
#pragma unroll
        for (int dg = 0; dg < 2; ++dg)
#pragma unroll
            for (int rb2 = 0; rb2 < 4; ++rb2) {
                uint2 pk;
                pk.x = packbf(Ot[dg][rb2 * 4 + 0] * inv,
                              Ot[dg][rb2 * 4 + 1] * inv);
                pk.y = packbf(Ot[dg][rb2 * 4 + 2] * inv,
                              Ot[dg][rb2 * 4 + 3] * inv);
                *(uint2*)(dst + dg * 32 + rb2 * 8) = pk;
            }
    }
}

// ---------------------------------------------------------------------------
extern "C" void kernel_launch(void* const* d_in, const int* in_sizes, int n_in,
                              void* d_out, int out_size, void* d_ws, size_t ws_size,
                              hipStream_t stream)
{
    const float* x  = (const float*)d_in[0];
    const float* Wq = (const float*)d_in[1];
    const float* bq = (const float*)d_in[2];
    const float* Wk = (const float*)d_in[3];
    const float* bk = (const float*)d_in[4];
    const float* Wv = (const float*)d_in[5];
    const float* bv = (const float*)d_in[6];
    const float* Wp = (const float*)d_in[7];
    const float* bp = (const float*)d_in[8];

    unsigned short* ws = (unsigned short*)d_ws;
    unsigned short* Qw  = ws;                  // Q' frag-linear, *log2e (8 MB)
    unsigned short* Kw  = Qw + 4194304;        // K' frag-linear
    unsigned short* VTw = Kw + 4194304;        // V' frag-linear
    unsigned short* Owb = VTw + 4194304;       // [b][ns][512] bf16 (attn out)
    unsigned short* xb  = Owb;                 // x bf16 — ALIASES Owb (dead by attn)
    unsigned short* wqb = Owb + 4194304;       // W bf16: 262144 shorts each
    unsigned short* wkb = wqb + 262144;
    unsigned short* wvb = wkb + 262144;
    unsigned short* wpb = wvb + 262144;

    cvt_kernel<<<dim3(2560), 256, 0, stream>>>(
        x, Wq, Wk, Wv, Wp, xb, wqb, wkb, wvb, wpb);
    qkv_kernel<<<dim3(12, 64), 256, 0, stream>>>(
        xb, wqb, wkb, wvb, bq, bk, bv, Qw, Kw, VTw);
    attn_kernel<<<dim3(32, 16), 512, 0, stream>>>(Qw, Kw, VTw, Owb);
    outproj_kernel<<<dim3(4, 64), 256, 0, stream>>>(Owb, wpb, bp, (float*)d_out);
}

// Round 11
// 159.108 us; speedup vs baseline: 1.0349x; 1.0349x over previous
//
#include <hip/hip_runtime.h>
#include <math.h>
#include <stdint.h>

#define SEQ  2048
#define LOG2E 1.4426950408889634f

typedef __attribute__((ext_vector_type(4))) float f32x4;
typedef __attribute__((ext_vector_type(16))) float f32x16;
typedef __attribute__((ext_vector_type(8))) short bf16x8;

template <int V> struct IC { static constexpr int value = V; };

// pack two fp32 -> bf16x2 dword via v_perm (round-half-up; ties-only diff vs RNE)
__device__ __forceinline__ unsigned packbf(float a, float b) {
    return __builtin_amdgcn_perm(__float_as_uint(b) + 0x8000u,
                                 __float_as_uint(a) + 0x8000u, 0x07060302u);
}

// async global->LDS, 16B/lane: LDS dest = wave-uniform base + lane*16 (HW),
// global source is per-lane.
__device__ __forceinline__ void gload16(const unsigned short* g, unsigned short* l) {
    __builtin_amdgcn_global_load_lds(
        (const __attribute__((address_space(1))) unsigned int*)g,
        (__attribute__((address_space(3))) unsigned int*)l, 16, 0, 0);
}

// ---------------------------------------------------------------------------
// Prepass: convert x (4.2M elems) and Wq/Wk/Wv/Wp (262144 each) fp32->bf16.
// ---------------------------------------------------------------------------
__global__ __launch_bounds__(256) void cvt_kernel(
    const float* __restrict__ x,  const float* __restrict__ wq,
    const float* __restrict__ wk, const float* __restrict__ wv,
    const float* __restrict__ wp,
    unsigned short* __restrict__ xb,  unsigned short* __restrict__ wqb,
    unsigned short* __restrict__ wkb, unsigned short* __restrict__ wvb,
    unsigned short* __restrict__ wpb)
{
    const int c = blockIdx.x * 256 + threadIdx.x;
    const float* s;
    unsigned short* d;
    int off;
    if (c < 524288) {                 // x: 4194304/8 chunks
        s = x; d = xb; off = c;
    } else {
        const int cc = c - 524288;
        const int wsel = cc >> 15;    // 0..3, 32768 chunks each
        off = cc & 32767;
        s = wsel == 0 ? wq : wsel == 1 ? wk : wsel == 2 ? wv : wp;
        d = wsel == 0 ? wqb : wsel == 1 ? wkb : wsel == 2 ? wvb : wpb;
    }
    const float4* sp = (const float4*)s + (size_t)off * 2;
    const float4 a = sp[0], b = sp[1];
    uint4 p;
    p.x = packbf(a.x, a.y); p.y = packbf(a.z, a.w);
    p.z = packbf(b.x, b.y); p.w = packbf(b.z, b.w);
    *((uint4*)d + off) = p;
}

// ---------------------------------------------------------------------------
// QKV GEMM, bf16 operands. C = x(M,512) @ W(N,512)^T + bias, N=1536 (Q|K|V),
// grid (12,64), 128x128 tiles, BK=64, reg-staged (R8 measured-best config).
// Frag-linear outputs (exact MFMA fragment image; attn reads straight from L2):
//   Q'/K': [bh][q32tile(64)][kt(4)][lane(64)][8]   (TR orientation; Q *LOG2E)
//   V'   : [bh][j64tile(32)][dg*4+p(8)][lane(64)][8]
// ---------------------------------------------------------------------------
__global__ __launch_bounds__(256, 3) void qkv_kernel(
    const unsigned short* __restrict__ xb, const unsigned short* __restrict__ wqb,
    const unsigned short* __restrict__ wkb, const unsigned short* __restrict__ wvb,
    const float* __restrict__ bq, const float* __restrict__ bk,
    const float* __restrict__ bv,
    unsigned short* __restrict__ Qw, unsigned short* __restrict__ Kw,
    unsigned short* __restrict__ VTw)
{
    __shared__ __align__(16) unsigned short smem[16384];  // As 8192 | Bs 8192
    unsigned short* As = smem;
    unsigned short* Bs = smem + 8192;

    const int t = threadIdx.x;
    const int w = t >> 6, lane = t & 63, quad = (t >> 4) & 3, l15 = t & 15;
    const int wr = w >> 1, wc = w & 1;
    const int m0 = blockIdx.y * 128;
    const int n0 = blockIdx.x * 128;
    const int which = n0 >> 9;                 // 0=Q 1=K 2=V
    const unsigned short* wbase = which == 0 ? wqb : (which == 1 ? wkb : wvb);
    const int nrow = n0 & 511;

    const int ar = t >> 2, ac = t & 3;         // row 0..63, chunk 0..3
    const unsigned short* ax = xb + (size_t)(m0 + ar) * 512 + ac * 8;
    const unsigned short* bx = wbase + (size_t)(nrow + ar) * 512 + ac * 8;
    const int lws = (ar & 15) | (ac << 4);
    const int off0 = (ar >> 4) * 512 + lws * 8;   // row ar, chunk ac, slab 0

    f32x4 acc[4][4];
#pragma unroll
    for (int mt = 0; mt < 4; ++mt)
#pragma unroll
        for (int nt = 0; nt < 4; ++nt) acc[mt][nt] = (f32x4){0.f, 0.f, 0.f, 0.f};

    uint4 ra0, ra1, ra2, ra3, rb0, rb1, rb2, rb3;
    auto loadt = [&](int k0) {
        ra0 = *(const uint4*)(ax + k0);
        ra1 = *(const uint4*)(ax + k0 + 32);
        ra2 = *(const uint4*)(ax + 32768 + k0);
        ra3 = *(const uint4*)(ax + 32768 + k0 + 32);
        rb0 = *(const uint4*)(bx + k0);
        rb1 = *(const uint4*)(bx + k0 + 32);
        rb2 = *(const uint4*)(bx + 32768 + k0);
        rb3 = *(const uint4*)(bx + 32768 + k0 + 32);
    };
    auto writet = [&]() {
        *(uint4*)(As + off0) = ra0;
        *(uint4*)(As + off0 + 4096) = ra1;
        *(uint4*)(As + off0 + 2048) = ra2;
        *(uint4*)(As + off0 + 2048 + 4096) = ra3;
        *(uint4*)(Bs + off0) = rb0;
        *(uint4*)(Bs + off0 + 4096) = rb1;
        *(uint4*)(Bs + off0 + 2048) = rb2;
        *(uint4*)(Bs + off0 + 2048 + 4096) = rb3;
    };

    loadt(0);
    auto kloop = [&](auto TRC) {
        constexpr int TR = decltype(TRC)::value;
        for (int ki = 0; ki < 8; ++ki) {
            writet();
            if (ki < 7) loadt((ki + 1) * 64);
            __syncthreads();
#pragma unroll
            for (int s = 0; s < 2; ++s) {
                bf16x8 af[4], bfr[4];
#pragma unroll
                for (int mt = 0; mt < 4; ++mt)
                    af[mt] = *(const bf16x8*)(As + s * 4096 +
                                              ((wr * 4 + mt) * 64 + lane) * 8);
#pragma unroll
                for (int nt = 0; nt < 4; ++nt)
                    bfr[nt] = *(const bf16x8*)(Bs + s * 4096 +
                                               ((wc * 4 + nt) * 64 + lane) * 8);
#pragma unroll
                for (int mt = 0; mt < 4; ++mt)
#pragma unroll
                    for (int nt = 0; nt < 4; ++nt) {
                        if (TR)
                            acc[mt][nt] = __builtin_amdgcn_mfma_f32_16x16x32_bf16(
                                bfr[nt], af[mt], acc[mt][nt], 0, 0, 0);
                        else
                            acc[mt][nt] = __builtin_amdgcn_mfma_f32_16x16x32_bf16(
                                af[mt], bfr[nt], acc[mt][nt], 0, 0, 0);
                    }
            }
            if (ki < 7) __syncthreads();
        }
    };
    if (which < 2) kloop(IC<1>{});
    else           kloop(IC<0>{});

    if (which == 2) {
        // V: normal orientation -> frag-linear V'
#pragma unroll
        for (int nt = 0; nt < 4; ++nt) {
            const int n = n0 + wc * 64 + nt * 16 + l15;
            const float bias = bv[n & 511];
            const int h = (n >> 6) & 7, d = n & 63;
#pragma unroll
            for (int mt = 0; mt < 4; ++mt) {
                const int mb = m0 + wr * 64 + mt * 16 + quad * 4;
                const int bi = mb >> 11, ns = mb & 2047;
                const int bhl = bi * 8 + h;
                const f32x4 v = acc[mt][nt];
                uint2 pk;
                pk.x = packbf(v[0] + bias, v[1] + bias);
                pk.y = packbf(v[2] + bias, v[3] + bias);
                const size_t off =
                    ((size_t)(bhl * 32 + (ns >> 6)) * 8 + ((d >> 5) << 2) +
                     ((ns >> 4) & 3)) * 512 +
                    ((d & 31) << 3) + ((ns & 8) << 5) + (ns & 7);
                *(uint2*)(VTw + off) = pk;
            }
        }
    } else {
        // Q/K: TR orientation -> frag-linear Q'/K'
        const float sc = which ? 1.f : LOG2E;
        const float* bpt = which ? bk : bq;
        unsigned short* base = which ? Kw : Qw;
#pragma unroll
        for (int nt = 0; nt < 4; ++nt) {
            const int nb = n0 + wc * 64 + nt * 16 + quad * 4;   // d base
            const f32x4 bvv = *(const f32x4*)(bpt + (nb & 511));
            const int h = (nb >> 6) & 7, d0 = nb & 63;
#pragma unroll
            for (int mt = 0; mt < 4; ++mt) {
                const int nsg = m0 + wr * 64 + mt * 16 + l15;   // ns (col=l15)
                const int bi = nsg >> 11, ns = nsg & 2047;
                const int bhl = bi * 8 + h;
                const f32x4 v = acc[mt][nt];
                uint2 pk;
                pk.x = packbf((v[0] + bvv[0]) * sc, (v[1] + bvv[1]) * sc);
                pk.y = packbf((v[2] + bvv[2]) * sc, (v[3] + bvv[3]) * sc);
                const size_t off =
                    ((size_t)(bhl * 64 + (ns >> 5)) * 4 + (d0 >> 4)) * 512 +
                    ((d0 & 8) << 5) + ((ns & 31) << 3) + (d0 & 7);
                *(uint2*)(base + off) = pk;
            }
        }
    }
}

// ---------------------------------------------------------------------------
// Out-projection GEMM: out = Owb(M,512) @ Wp(512,512)^T + bp, fp32 out.
// 128x128 tiles, grid (4,64), BK=64, reg-staged (R8 config).
// ---------------------------------------------------------------------------
__global__ __launch_bounds__(256, 3) void outproj_kernel(
    const unsigned short* __restrict__ Aw, const unsigned short* __restrict__ wpb,
    const float* __restrict__ bp, float* __restrict__ out)
{
    __shared__ __align__(16) unsigned short smem[16384];  // As 8192 | Bs 8192
    unsigned short* As = smem;
    unsigned short* Bs = smem + 8192;

    const int t = threadIdx.x;
    const int w = t >> 6, lane = t & 63, quad = (t >> 4) & 3, l15 = t & 15;
    const int wr = w >> 1, wc = w & 1;
    const int m0 = blockIdx.y * 128;
    const int n0 = blockIdx.x * 128;

    const int ar = t >> 2, ac = t & 3;
    const unsigned short* ap = Aw + (size_t)(m0 + ar) * 512 + ac * 8;
    const unsigned short* bx = wpb + (size_t)(n0 + ar) * 512 + ac * 8;
    const int lws = (ar & 15) | (ac << 4);
    const int off0 = (ar >> 4) * 512 + lws * 8;

    f32x4 acc[4][4];
#pragma unroll
    for (int mt = 0; mt < 4; ++mt)
#pragma unroll
        for (int nt = 0; nt < 4; ++nt) acc[mt][nt] = (f32x4){0.f, 0.f, 0.f, 0.f};

    uint4 ra0, ra1, ra2, ra3, rb0, rb1, rb2, rb3;
    auto loadt = [&](int k0) {
        ra0 = *(const uint4*)(ap + k0);
        ra1 = *(const uint4*)(ap + k0 + 32);
        ra2 = *(const uint4*)(ap + 32768 + k0);
        ra3 = *(const uint4*)(ap + 32768 + k0 + 32);
        rb0 = *(const uint4*)(bx + k0);
        rb1 = *(const uint4*)(bx + k0 + 32);
        rb2 = *(const uint4*)(bx + 32768 + k0);
        rb3 = *(const uint4*)(bx + 32768 + k0 + 32);
    };
    auto writet = [&]() {
        *(uint4*)(As + off0) = ra0;
        *(uint4*)(As + off0 + 4096) = ra1;
        *(uint4*)(As + off0 + 2048) = ra2;
        *(uint4*)(As + off0 + 2048 + 4096) = ra3;
        *(uint4*)(Bs + off0) = rb0;
        *(uint4*)(Bs + off0 + 4096) = rb1;
        *(uint4*)(Bs + off0 + 2048) = rb2;
        *(uint4*)(Bs + off0 + 2048 + 4096) = rb3;
    };

    loadt(0);
    for (int ki = 0; ki < 8; ++ki) {
        writet();
        if (ki < 7) loadt((ki + 1) * 64);
        __syncthreads();
#pragma unroll
        for (int s = 0; s < 2; ++s) {
            bf16x8 af[4], bfr[4];
#pragma unroll
            for (int mt = 0; mt < 4; ++mt)
                af[mt] = *(const bf16x8*)(As + s * 4096 +
                                          ((wr * 4 + mt) * 64 + lane) * 8);
#pragma unroll
            for (int nt = 0; nt < 4; ++nt)
                bfr[nt] = *(const bf16x8*)(Bs + s * 4096 +
                                           ((wc * 4 + nt) * 64 + lane) * 8);
#pragma unroll
            for (int mt = 0; mt < 4; ++mt)
#pragma unroll
                for (int nt = 0; nt < 4; ++nt)
                    acc[mt][nt] = __builtin_amdgcn_mfma_f32_16x16x32_bf16(
                        af[mt], bfr[nt], acc[mt][nt], 0, 0, 0);
        }
        if (ki < 7) __syncthreads();
    }

#pragma unroll
    for (int nt = 0; nt < 4; ++nt) {
        const int n = n0 + wc * 64 + nt * 16 + l15;
        const float bias = bp[n];
#pragma unroll
        for (int mt = 0; mt < 4; ++mt) {
            const int mb = m0 + wr * 64 + mt * 16 + quad * 4;
            const f32x4 v = acc[mt][nt];
#pragma unroll
            for (int r = 0; r < 4; ++r)
                out[(size_t)(mb + r) * 512 + n] = v[r] + bias;
        }
    }
}

// ---------------------------------------------------------------------------
// bf16 32x32x16-MFMA flash attention, R11: LDS-STAGED K/V.
// Diagnosis: every wave was loading its own K/V frags from L2 — 8 KB/wave-step
// x 131072 wave-steps = 1 GB of L2 reads in 48 us = ~22 TB/s = ~63% of the
// 34.5 TB/s L2 ceiling. Each K/V element was read 64x (16 qblk blocks x 4
// same-jh waves). That shared-queue wall explains why occupancy/pipelining/
// prefetch/desync were all null.
// Fix: block stages each 64-key tile's K (8 KB) + V (8 KB) into LDS once via
// gload16 (frag image is tile-contiguous -> linear copy, 2 loads/thread),
// double-buffered; waves ds_read frags (stride-1, conflict-free) at 69 TB/s.
// L2 reads drop 4x. One barrier/tile; stage issued at loop top has the whole
// compute phase to land. KV dbuf (32 KB) aliases the end-merge cb (33 KB).
// Grid (32,16) x 512 thr, (512,2). T12 P-frag kept. S-pipeline dropped
// (bought ~0; frags now come from LDS).
// att = softmax(unscaled)/sqrt(512)
// ---------------------------------------------------------------------------
__global__ __launch_bounds__(512, 2) void attn_kernel(
    const unsigned short* __restrict__ Qf, const unsigned short* __restrict__ Kf,
    const unsigned short* __restrict__ Vf, unsigned short* __restrict__ Ow)
{
    __shared__ __align__(16) float cb[8448];        // 33792 B; loop aliases as KV dbuf
    unsigned short* kv = (unsigned short*)cb;       // kv[2][8192]: K at +0, V at +4096

    const int t = threadIdx.x;
    const int w = t >> 6, lane = t & 63;
    const int l31 = lane & 31, hlf = lane >> 5;
    const int qi = w >> 1, jh = w & 1;

    const int bh = blockIdx.x;          // bh%8 pins one (b,h) to one XCD
    const int qblk = blockIdx.y;        // 0..15
    const int q0 = qblk * 128;

    const unsigned short* Kt = Kf + (size_t)bh * 131072;   // tile stride 4096
    const unsigned short* Vt = Vf + (size_t)bh * 131072;

    const int qgg = qblk * 4 + qi;
    const unsigned short* Qp = Qf + ((size_t)(bh * 64 + qgg) * 4) * 512 + lane * 8;
    bf16x8 qf[4];
#pragma unroll
    for (int kt = 0; kt < 4; ++kt)
        qf[kt] = *(const bf16x8*)(Qp + kt * 512);

    f32x16 zero;
#pragma unroll
    for (int r = 0; r < 16; ++r) zero[r] = 0.f;

    float lpart = 0.f;
    f32x16 Ot[2];
    Ot[0] = zero; Ot[1] = zero;

    // wave w stages 512-short chunk w of K and of V (1 KB each, linear)
    auto stage = [&](int b, int jt) {
        unsigned short* dst = kv + b * 8192 + w * 512;
        gload16(Kt + (size_t)jt * 4096 + w * 512 + lane * 8, dst);
        gload16(Vt + (size_t)jt * 4096 + w * 512 + lane * 8, dst + 4096);
    };

    stage(0, 0);
    __syncthreads();                    // buf0 ready
    int cur = 0;

    for (int jt = 0; jt < 32; ++jt) {
        if (jt < 31) stage(cur ^ 1, jt + 1);   // async loads overlap compute

        const unsigned short* kb = kv + cur * 8192;
        bf16x8 kc[4], vc[4];
#pragma unroll
        for (int c = 0; c < 4; ++c)
            kc[c] = *(const bf16x8*)(kb + (jh * 4 + c) * 512 + lane * 8);
#pragma unroll
        for (int dg = 0; dg < 2; ++dg)
#pragma unroll
            for (int p = 0; p < 2; ++p)
                vc[dg * 2 + p] = *(const bf16x8*)(
                    kb + 4096 + (dg * 4 + jh * 2 + p) * 512 + lane * 8);

        // S^T for this wave's q-group
        f32x16 st = zero;
        __builtin_amdgcn_s_setprio(1);
#pragma unroll
        for (int kt = 0; kt < 4; ++kt)
            st = __builtin_amdgcn_mfma_f32_32x32x16_bf16(kc[kt], qf[kt], st, 0, 0, 0);
        __builtin_amdgcn_s_setprio(0);

        // p = 2^s (no max subtraction; logits bounded); tree-summed l
#pragma unroll
        for (int r = 0; r < 16; ++r)
            st[r] = __builtin_amdgcn_exp2f(st[r]);
        {
            float s01 = st[0] + st[1],   s23 = st[2] + st[3];
            float s45 = st[4] + st[5],   s67 = st[6] + st[7];
            float s89 = st[8] + st[9],   sAB = st[10] + st[11];
            float sCD = st[12] + st[13], sEF = st[14] + st[15];
            lpart += ((s01 + s23) + (s45 + s67)) + ((s89 + sAB) + (sCD + sEF));
        }

        // P^T -> B-frag: cvt_pk (RNE) + permlane32_swap half-exchange (T12)
#pragma unroll
        for (int p = 0; p < 2; ++p) {
            const int r0 = p * 8;
            unsigned a0, a1, b0, b1;
            asm("v_cvt_pk_bf16_f32 %0, %1, %2"
                : "=v"(a0) : "v"(st[r0 + 0]), "v"(st[r0 + 1]));
            asm("v_cvt_pk_bf16_f32 %0, %1, %2"
                : "=v"(a1) : "v"(st[r0 + 2]), "v"(st[r0 + 3]));
            asm("v_cvt_pk_bf16_f32 %0, %1, %2"
                : "=v"(b0) : "v"(st[r0 + 4]), "v"(st[r0 + 5]));
            asm("v_cvt_pk_bf16_f32 %0, %1, %2"
                : "=v"(b1) : "v"(st[r0 + 6]), "v"(st[r0 + 7]));
            asm("v_permlane32_swap_b32 %0, %1" : "+v"(a0), "+v"(b0));
            asm("v_permlane32_swap_b32 %0, %1" : "+v"(a1), "+v"(b1));
            union { unsigned u[4]; bf16x8 v; } pb;
            pb.u[0] = a0;
            pb.u[1] = a1;
            pb.u[2] = b0;
            pb.u[3] = b1;
            __builtin_amdgcn_s_setprio(1);
            Ot[0] = __builtin_amdgcn_mfma_f32_32x32x16_bf16(vc[0 + p], pb.v, Ot[0], 0, 0, 0);
            Ot[1] = __builtin_amdgcn_mfma_f32_32x32x16_bf16(vc[2 + p], pb.v, Ot[1], 0, 0, 0);
            __builtin_amdgcn_s_setprio(0);
        }

        __syncthreads();                // next buf staged + this buf free
        cur ^= 1;
    }

    // ---- merge (O, l) across the jh pair; jh=0 stores ----
    // (kv buffers dead; cb aliases them — final loop barrier protects)
    if (jh == 1) {
#pragma unroll
        for (int dg = 0; dg < 2; ++dg) {
            const int cidx = (qi * 2 + dg) * 4;
#pragma unroll
            for (int k = 0; k < 4; ++k) {
                float4 v = make_float4(
                    Ot[dg][k * 4 + 0], Ot[dg][k * 4 + 1],
                    Ot[dg][k * 4 + 2], Ot[dg][k * 4 + 3]);
                *(float4*)(cb + (cidx + k) * 256 + lane * 4) = v;
            }
        }
        cb[8192 + qi * 64 + lane] = lpart;
    }
    __syncthreads();
    if (jh == 0) {
        const int bi = bh >> 3, h = bh & 7;
#pragma unroll
        for (int dg = 0; dg < 2; ++dg) {
            const int cidx = (qi * 2 + dg) * 4;
#pragma unroll
            for (int k = 0; k < 4; ++k) {
                const float4 v = *(const float4*)(cb + (cidx + k) * 256 + lane * 4);
                Ot[dg][k * 4 + 0] += v.x;
                Ot[dg][k * 4 + 1] += v.y;
                Ot[dg][k * 4 + 2] += v.z;
                Ot[dg][k * 4 + 3] += v.w;
            }
        }
        float lv = lpart + cb[8192 + qi * 64 + lane];
        lv += __shfl_xor(lv, 32);
        const float inv = 1.0f / (lv * 22.627416997969522f);

        const int ns = q0 + qi * 32 + l31;
        unsigned short* dst = Ow + ((size_t)bi * SEQ + ns) * 512 + h * 64 + hlf * 4;
#pragma unroll
        for (int dg = 0; dg < 2; ++dg)
#pragma unroll
            for (int rb2 = 0; rb2 < 4; ++rb2) {
                uint2 pk;
                pk.x = packbf(Ot[dg][rb2 * 4 + 0] * inv,
                              Ot[dg][rb2 * 4 + 1] * inv);
                pk.y = packbf(Ot[dg][rb2 * 4 + 2] * inv,
                              Ot[dg][rb2 * 4 + 3] * inv);
                *(uint2*)(dst + dg * 32 + rb2 * 8) = pk;
            }
    }
}

// ---------------------------------------------------------------------------
extern "C" void kernel_launch(void* const* d_in, const int* in_sizes, int n_in,
                              void* d_out, int out_size, void* d_ws, size_t ws_size,
                              hipStream_t stream)
{
    const float* x  = (const float*)d_in[0];
    const float* Wq = (const float*)d_in[1];
    const float* bq = (const float*)d_in[2];
    const float* Wk = (const float*)d_in[3];
    const float* bk = (const float*)d_in[4];
    const float* Wv = (const float*)d_in[5];
    const float* bv = (const float*)d_in[6];
    const float* Wp = (const float*)d_in[7];
    const float* bp = (const float*)d_in[8];

    unsigned short* ws = (unsigned short*)d_ws;
    unsigned short* Qw  = ws;                  // Q' frag-linear, *log2e (8 MB)
    unsigned short* Kw  = Qw + 4194304;        // K' frag-linear
    unsigned short* VTw = Kw + 4194304;        // V' frag-linear
    unsigned short* Owb = VTw + 4194304;       // [b][ns][512] bf16 (attn out)
    unsigned short* xb  = Owb;                 // x bf16 — ALIASES Owb (dead by attn)
    unsigned short* wqb = Owb + 4194304;       // W bf16: 262144 shorts each
    unsigned short* wkb = wqb + 262144;
    unsigned short* wvb = wkb + 262144;
    unsigned short* wpb = wvb + 262144;

    cvt_kernel<<<dim3(2560), 256, 0, stream>>>(
        x, Wq, Wk, Wv, Wp, xb, wqb, wkb, wvb, wpb);
    qkv_kernel<<<dim3(12, 64), 256, 0, stream>>>(
        xb, wqb, wkb, wvb, bq, bk, bv, Qw, Kw, VTw);
    attn_kernel<<<dim3(32, 16), 512, 0, stream>>>(Qw, Kw, VTw, Owb);
    outproj_kernel<<<dim3(4, 64), 256, 0, stream>>>(Owb, wpb, bp, (float*)d_out);
}